// Round 9
// baseline (178.313 us; speedup 1.0000x reference)
//
#include <hip/hip_runtime.h>
#include <hip/hip_bf16.h>

// Problem constants
#define GAT_IN   128
#define GAT_OUT  128   // H*C
#define GAT_H    4
#define GAT_C    32
#define NEG_SLOPE 0.2f
#define BUCKET   96    // per-node edge slot capacity; P(Poisson(12) >= 96) ~ 1e-60

typedef __attribute__((ext_vector_type(8))) short bf16x8;
typedef __attribute__((ext_vector_type(4))) float f32x4;
union U4 { uint4 u; bf16x8 v; };

static __device__ __forceinline__ unsigned int pack_bf16(float lo, float hi) {
    __hip_bfloat16 a = __float2bfloat16(lo);   // RTN
    __hip_bfloat16 b = __float2bfloat16(hi);
    unsigned short ua = *reinterpret_cast<unsigned short*>(&a);
    unsigned short ub = *reinterpret_cast<unsigned short*>(&b);
    return (unsigned int)ua | ((unsigned int)ub << 16);
}

// ---------------------------------------------------------------------------
// Kernel 1: Bezier interpolation of params + zero cnt[] (harness poisons ws).
// Emits W as bf16 in MFMA B-fragment order:
//   wfrag uint index = ((nt*4 + ks)*64 + lane)*4 + jw
//   holds W[o = nt*16 + (lane&15)][k = ks*32 + (lane>>4)*8 + jw*2 .. +1]
// ---------------------------------------------------------------------------
__global__ __launch_bounds__(256) void interp_kernel(
    const float* __restrict__ coeffs,
    const float* __restrict__ lw,   // [3,128,128]
    const float* __restrict__ lb,   // [3,128]
    const float* __restrict__ asr,  // [3,1,4,32]
    const float* __restrict__ ads,  // [3,1,4,32]
    unsigned int* __restrict__ wfrag,  // 8192 uints (32 KB)
    float* __restrict__ biasc,
    float* __restrict__ asrc, float* __restrict__ adst,
    int* __restrict__ cnt, int n)
{
    int i = blockIdx.x * 256 + threadIdx.x;
    float c0 = coeffs[0], c1 = coeffs[1], c2 = coeffs[2];
    if (i < 8192) {
        int lane = (i >> 2) & 63;
        int nk   = i >> 8;           // nt*4 + ks
        int jw   = i & 3;
        int nt = nk >> 2, ks = nk & 3;
        int o = nt * 16 + (lane & 15);
        int k = ks * 32 + (lane >> 4) * 8 + jw * 2;
        int idx = o * 128 + k;
        float w0 = c0 * lw[idx]     + c1 * lw[16384 + idx]     + c2 * lw[32768 + idx];
        float w1 = c0 * lw[idx + 1] + c1 * lw[16384 + idx + 1] + c2 * lw[32768 + idx + 1];
        wfrag[i] = pack_bf16(w0, w1);
    }
    if (i < 128) {
        biasc[i] = c0 * lb[i]  + c1 * lb[128 + i]  + c2 * lb[256 + i];
        asrc[i]  = c0 * asr[i] + c1 * asr[128 + i] + c2 * asr[256 + i];
        adst[i]  = c0 * ads[i] + c1 * ads[128 + i] + c2 * ads[256 + i];
    }
    if (i < n) cnt[i] = 0;
}

// ---------------------------------------------------------------------------
// Kernel 2 (FUSED): bucket scatter + MFMA GEMM. The two are independent
// (scatter: ei/cnt/esrc; gemm: x/wfrag/xtb) — issuing the scatter slice
// first puts its atomics+scattered stores in flight, hidden under the MFMA
// tile work across resident waves. gemm part: block = 4 waves x 16 rows =
// 64 rows, full 128 cols (x read ONCE per row — R5 lesson: head-split
// re-reads x across XCD-disjoint L2s). A-frags from fp32 x with in-register
// cvt; B-frags from wfrag (L2-resident). Epilogue stages f32 acc through
// LDS; each lane owns one (row, head) 32-col segment.
// ---------------------------------------------------------------------------
__global__ __launch_bounds__(256) void gemm_bucket_kernel(
    const float* __restrict__ x,       // [N,128] fp32
    const unsigned int* __restrict__ wfrag,
    const float* __restrict__ biasc,
    const float* __restrict__ asrc,
    const float* __restrict__ adst,
    unsigned int* __restrict__ xtb,    // [N,64] uints = [N,128] bf16
    float* __restrict__ alpha_src,     // [N,4]
    float* __restrict__ alpha_dst,     // [N,4]
    const int* __restrict__ ei,        // [2,E]
    int* __restrict__ cnt,             // [N] (zeroed by interp)
    int* __restrict__ esrc,            // [N,BUCKET]
    int n, int ne, int epb)
{
    __shared__ __align__(16) float C[64 * 132];   // 33 KB, stride 132 (pad)
    int tid  = threadIdx.x;

    // ---- bucket scatter slice (independent of gemm; latency overlaps) ----
    {
        int e0 = blockIdx.x * epb;
        int e1 = e0 + epb; if (e1 > ne) e1 = ne;
        for (int e = e0 + tid; e < e1; e += 256) {
            int row = ei[e], col = ei[ne + e];
            int pos = atomicAdd(&cnt[col], 1);
            if (pos < BUCKET) esrc[col * BUCKET + pos] = row;
        }
    }

    // ---- MFMA GEMM tile ----
    int lane = tid & 63;
    int wave = tid >> 6;
    int quad = lane >> 4;
    int lm   = lane & 15;
    int m0   = blockIdx.x * 64 + wave * 16;

    f32x4 acc[8];
    #pragma unroll
    for (int t = 0; t < 8; ++t) acc[t] = (f32x4){0.f, 0.f, 0.f, 0.f};

    int arow = m0 + lm; if (arow >= n) arow = n - 1;   // clamp (stores masked)
    const float4* xr = (const float4*)(x + (size_t)arow * 128 + quad * 8);
    const uint4*  wf = (const uint4*)wfrag;

    #pragma unroll
    for (int ks = 0; ks < 4; ++ks) {
        float4 a0 = xr[ks * 8 + 0];    // k = ks*32 + quad*8 + 0..3
        float4 a1 = xr[ks * 8 + 1];    // k = ks*32 + quad*8 + 4..7
        U4 af;
        af.u.x = pack_bf16(a0.x, a0.y);
        af.u.y = pack_bf16(a0.z, a0.w);
        af.u.z = pack_bf16(a1.x, a1.y);
        af.u.w = pack_bf16(a1.z, a1.w);
        #pragma unroll
        for (int nt = 0; nt < 8; ++nt) {
            U4 bf; bf.u = wf[(nt * 4 + ks) * 64 + lane];
            acc[nt] = __builtin_amdgcn_mfma_f32_16x16x32_bf16(
                af.v, bf.v, acc[nt], 0, 0, 0);
        }
    }

    // stage accumulators to LDS: C/D layout col = lane&15, row = quad*4+reg
    #pragma unroll
    for (int nt = 0; nt < 8; ++nt) {
        int col = nt * 16 + lm;
        #pragma unroll
        for (int r = 0; r < 4; ++r) {
            int rowl = wave * 16 + quad * 4 + r;
            C[rowl * 132 + col] = acc[nt][r];
        }
    }
    __syncthreads();

    // epilogue: 4 lanes per row; lane's segment = head (seg = lane&3)
    int rowl = wave * 16 + (lane >> 2);
    int seg  = lane & 3;
    int mrow = blockIdx.x * 64 + rowl;
    if (mrow < n) {
        const float4* cb = (const float4*)(C + rowl * 132 + seg * 32);
        const float4* bb = (const float4*)(biasc + seg * 32);
        const float4* sb = (const float4*)(asrc + seg * 32);
        const float4* db = (const float4*)(adst + seg * 32);
        float s = 0.f, d = 0.f;
        unsigned int ow[16];
        #pragma unroll
        for (int q = 0; q < 8; ++q) {
            float4 v = cb[q];
            float4 b = bb[q];
            v.x += b.x; v.y += b.y; v.z += b.z; v.w += b.w;
            float4 as = sb[q], ad = db[q];
            s += v.x * as.x + v.y * as.y + v.z * as.z + v.w * as.w;
            d += v.x * ad.x + v.y * ad.y + v.z * ad.z + v.w * ad.w;
            ow[q * 2 + 0] = pack_bf16(v.x, v.y);
            ow[q * 2 + 1] = pack_bf16(v.z, v.w);
        }
        alpha_src[mrow * 4 + seg] = s;
        alpha_dst[mrow * 4 + seg] = d;
        uint4* xo = (uint4*)(xtb + (size_t)mrow * 64 + seg * 16);
        #pragma unroll
        for (int q4 = 0; q4 < 4; ++q4)
            xo[q4] = make_uint4(ow[q4 * 4], ow[q4 * 4 + 1],
                                ow[q4 * 4 + 2], ow[q4 * 4 + 3]);
    }
}

// ---------------------------------------------------------------------------
// Kernel 3: fused softmax + aggregation. One wave per node, 2 ch/lane.
// Bucket indices loaded as int4 (wave-uniform -> scalar path); edge loop
// unrolled x8 with loads grouped ahead of compute for deep MLP. All index
// math 32-bit so gathers take the saddr+voffset global_load form.
// ---------------------------------------------------------------------------
__device__ __forceinline__ void edge_math(
    unsigned int r, unsigned int h, unsigned int lane, float ad,
    const unsigned int* __restrict__ xtb,
    const float* __restrict__ alpha_src,
    float& den, float& acc0, float& acc1)
{
    float as = alpha_src[(r << 2) | h];
    unsigned int u = xtb[(r << 6) | lane];
    float a = as + ad;
    a = fmaxf(a, NEG_SLOPE * a);              // leaky-relu, branchless
    float ex = __expf(a);
    den += ex;
    acc0 = fmaf(ex, __uint_as_float(u << 16), acc0);
    acc1 = fmaf(ex, __uint_as_float(u & 0xFFFF0000u), acc1);
}

__global__ __launch_bounds__(256) void agg_kernel(
    const int* __restrict__ cnt,
    const int* __restrict__ esrc,
    const unsigned int* __restrict__ xtb,   // [N,64] uints (bf16 pairs)
    const float* __restrict__ alpha_src,
    const float* __restrict__ alpha_dst,
    float* __restrict__ out,          // [N,128]
    int n)
{
    int node = blockIdx.x * 4 + (threadIdx.x >> 6);
    if (node >= n) return;
    unsigned int lane = threadIdx.x & 63;
    unsigned int h = lane >> 4;

    float ad = alpha_dst[((unsigned)node << 2) | h];
    const int* eb = esrc + node * BUCKET;
    int m = cnt[node]; if (m > BUCKET) m = BUCKET;

    float acc0 = 0.f, acc1 = 0.f, den = 0.f;
    int j = 0;
    for (; j + 8 <= m; j += 8) {
        int4 ra = *(const int4*)(eb + j);       // wave-uniform -> scalar load
        int4 rb = *(const int4*)(eb + j + 4);
        float as0 = alpha_src[((unsigned)ra.x << 2) | h];
        float as1 = alpha_src[((unsigned)ra.y << 2) | h];
        float as2 = alpha_src[((unsigned)ra.z << 2) | h];
        float as3 = alpha_src[((unsigned)ra.w << 2) | h];
        float as4 = alpha_src[((unsigned)rb.x << 2) | h];
        float as5 = alpha_src[((unsigned)rb.y << 2) | h];
        float as6 = alpha_src[((unsigned)rb.z << 2) | h];
        float as7 = alpha_src[((unsigned)rb.w << 2) | h];
        unsigned int u0 = xtb[((unsigned)ra.x << 6) | lane];
        unsigned int u1 = xtb[((unsigned)ra.y << 6) | lane];
        unsigned int u2 = xtb[((unsigned)ra.z << 6) | lane];
        unsigned int u3 = xtb[((unsigned)ra.w << 6) | lane];
        unsigned int u4 = xtb[((unsigned)rb.x << 6) | lane];
        unsigned int u5 = xtb[((unsigned)rb.y << 6) | lane];
        unsigned int u6 = xtb[((unsigned)rb.z << 6) | lane];
        unsigned int u7 = xtb[((unsigned)rb.w << 6) | lane];
        float a0 = fmaxf(as0 + ad, NEG_SLOPE * (as0 + ad));
        float a1 = fmaxf(as1 + ad, NEG_SLOPE * (as1 + ad));
        float a2 = fmaxf(as2 + ad, NEG_SLOPE * (as2 + ad));
        float a3 = fmaxf(as3 + ad, NEG_SLOPE * (as3 + ad));
        float a4 = fmaxf(as4 + ad, NEG_SLOPE * (as4 + ad));
        float a5 = fmaxf(as5 + ad, NEG_SLOPE * (as5 + ad));
        float a6 = fmaxf(as6 + ad, NEG_SLOPE * (as6 + ad));
        float a7 = fmaxf(as7 + ad, NEG_SLOPE * (as7 + ad));
        float e0 = __expf(a0), e1 = __expf(a1), e2 = __expf(a2), e3 = __expf(a3);
        float e4 = __expf(a4), e5 = __expf(a5), e6 = __expf(a6), e7 = __expf(a7);
        den += ((e0 + e1) + (e2 + e3)) + ((e4 + e5) + (e6 + e7));
        acc0 = fmaf(e0, __uint_as_float(u0 << 16),
               fmaf(e1, __uint_as_float(u1 << 16),
               fmaf(e2, __uint_as_float(u2 << 16),
               fmaf(e3, __uint_as_float(u3 << 16),
               fmaf(e4, __uint_as_float(u4 << 16),
               fmaf(e5, __uint_as_float(u5 << 16),
               fmaf(e6, __uint_as_float(u6 << 16),
               fmaf(e7, __uint_as_float(u7 << 16), acc0))))))));
        acc1 = fmaf(e0, __uint_as_float(u0 & 0xFFFF0000u),
               fmaf(e1, __uint_as_float(u1 & 0xFFFF0000u),
               fmaf(e2, __uint_as_float(u2 & 0xFFFF0000u),
               fmaf(e3, __uint_as_float(u3 & 0xFFFF0000u),
               fmaf(e4, __uint_as_float(u4 & 0xFFFF0000u),
               fmaf(e5, __uint_as_float(u5 & 0xFFFF0000u),
               fmaf(e6, __uint_as_float(u6 & 0xFFFF0000u),
               fmaf(e7, __uint_as_float(u7 & 0xFFFF0000u), acc1))))))));
    }
    if (j + 4 <= m) {
        int4 ra = *(const int4*)(eb + j);
        edge_math(ra.x, h, lane, ad, xtb, alpha_src, den, acc0, acc1);
        edge_math(ra.y, h, lane, ad, xtb, alpha_src, den, acc0, acc1);
        edge_math(ra.z, h, lane, ad, xtb, alpha_src, den, acc0, acc1);
        edge_math(ra.w, h, lane, ad, xtb, alpha_src, den, acc0, acc1);
        j += 4;
    }
    for (; j < m; ++j)
        edge_math(eb[j], h, lane, ad, xtb, alpha_src, den, acc0, acc1);

    float inv = 1.0f / (den + 1e-16f);
    ((float2*)out)[((unsigned)node << 6) | lane] = make_float2(acc0 * inv, acc1 * inv);
}

// ---------------------------------------------------------------------------
extern "C" void kernel_launch(void* const* d_in, const int* in_sizes, int n_in,
                              void* d_out, int out_size, void* d_ws, size_t ws_size,
                              hipStream_t stream)
{
    const float* x      = (const float*)d_in[0];
    const int*   ei     = (const int*)  d_in[1];
    const float* coeffs = (const float*)d_in[2];
    const float* lw     = (const float*)d_in[3];
    const float* lb     = (const float*)d_in[4];
    const float* asr    = (const float*)d_in[5];
    const float* ads    = (const float*)d_in[6];
    float* out = (float*)d_out;

    int n  = in_sizes[0] / GAT_IN;     // 50000
    int ne = in_sizes[1] / 2;          // 600000
    int gb  = (n + 63) / 64;           // gemm/bucket blocks (782)
    int epb = (ne + gb - 1) / gb;      // edges per block (768)

    // workspace layout (16B-aligned segments)
    float* ws        = (float*)d_ws;
    unsigned int* wfrag = (unsigned int*)ws;      // 8192 uints (32 KB)
    float* biasc     = ws + 16384;                // 128
    float* asrc      = ws + 16512;                // 128
    float* adst      = ws + 16640;                // 128
    unsigned int* xtb = (unsigned int*)(ws + 16768);      // n*64 uints
    float* alpha_src = (float*)(xtb + (size_t)n * 64);    // n*4
    float* alpha_dst = alpha_src + (size_t)n * 4;         // n*4
    int*   cnt       = (int*)(alpha_dst + (size_t)n * 4); // n
    int*   esrc      = cnt + n;                   // n*BUCKET

    // 1. interpolate params (W in B-frag bf16 order) + zero cnt
    int zb = (n + 255) / 256; if (zb < 64) zb = 64;
    interp_kernel<<<zb, 256, 0, stream>>>(coeffs, lw, lb, asr, ads,
                                          wfrag, biasc, asrc, adst, cnt, n);
    // 2. fused bucket scatter + MFMA GEMM (+alpha)
    gemm_bucket_kernel<<<gb, 256, 0, stream>>>(
        x, wfrag, biasc, asrc, adst, xtb, alpha_src, alpha_dst,
        ei, cnt, esrc, n, ne, epb);
    // 3. fused softmax + aggregation
    agg_kernel<<<(n + 3) / 4, 256, 0, stream>>>(
        cnt, esrc, xtb, alpha_src, alpha_dst, out, n);
}

// Round 10
// 167.671 us; speedup vs baseline: 1.0635x; 1.0635x over previous
//
#include <hip/hip_runtime.h>
#include <hip/hip_bf16.h>

// Problem constants
#define GAT_IN   128
#define GAT_OUT  128   // H*C
#define GAT_H    4
#define GAT_C    32
#define NEG_SLOPE 0.2f
#define BUCKET   96    // per-node edge slot capacity; P(Poisson(12) >= 96) ~ 1e-60

typedef __attribute__((ext_vector_type(8))) short bf16x8;
typedef __attribute__((ext_vector_type(4))) float f32x4;
union U4 { uint4 u; bf16x8 v; };

static __device__ __forceinline__ unsigned int pack_bf16(float lo, float hi) {
    __hip_bfloat16 a = __float2bfloat16(lo);   // RTN
    __hip_bfloat16 b = __float2bfloat16(hi);
    unsigned short ua = *reinterpret_cast<unsigned short*>(&a);
    unsigned short ub = *reinterpret_cast<unsigned short*>(&b);
    return (unsigned int)ua | ((unsigned int)ub << 16);
}

// ---------------------------------------------------------------------------
// Kernel 1: Bezier interpolation of params + zero cnt[] (harness poisons ws).
// Emits W as bf16 in MFMA B-fragment order:
//   wfrag uint index = ((nt*4 + ks)*64 + lane)*4 + jw
//   holds W[o = nt*16 + (lane&15)][k = ks*32 + (lane>>4)*8 + jw*2 .. +1]
// ---------------------------------------------------------------------------
__global__ __launch_bounds__(256) void interp_kernel(
    const float* __restrict__ coeffs,
    const float* __restrict__ lw,   // [3,128,128]
    const float* __restrict__ lb,   // [3,128]
    const float* __restrict__ asr,  // [3,1,4,32]
    const float* __restrict__ ads,  // [3,1,4,32]
    unsigned int* __restrict__ wfrag,  // 8192 uints (32 KB)
    float* __restrict__ biasc,
    float* __restrict__ asrc, float* __restrict__ adst,
    int* __restrict__ cnt, int n)
{
    int i = blockIdx.x * 256 + threadIdx.x;
    float c0 = coeffs[0], c1 = coeffs[1], c2 = coeffs[2];
    if (i < 8192) {
        int lane = (i >> 2) & 63;
        int nk   = i >> 8;           // nt*4 + ks
        int jw   = i & 3;
        int nt = nk >> 2, ks = nk & 3;
        int o = nt * 16 + (lane & 15);
        int k = ks * 32 + (lane >> 4) * 8 + jw * 2;
        int idx = o * 128 + k;
        float w0 = c0 * lw[idx]     + c1 * lw[16384 + idx]     + c2 * lw[32768 + idx];
        float w1 = c0 * lw[idx + 1] + c1 * lw[16384 + idx + 1] + c2 * lw[32768 + idx + 1];
        wfrag[i] = pack_bf16(w0, w1);
    }
    if (i < 128) {
        biasc[i] = c0 * lb[i]  + c1 * lb[128 + i]  + c2 * lb[256 + i];
        asrc[i]  = c0 * asr[i] + c1 * asr[128 + i] + c2 * asr[256 + i];
        adst[i]  = c0 * ads[i] + c1 * ads[128 + i] + c2 * ads[256 + i];
    }
    if (i < n) cnt[i] = 0;
}

// ---------------------------------------------------------------------------
// Kernel 2: xt = x @ W^T + bias via MFMA bf16. Block = 4 waves x 16 rows
// = 64 rows, full 128 cols (x read ONCE per row — R5 lesson: head-split
// re-reads x across XCD-disjoint L2s). A-frags from fp32 x with in-register
// cvt; B-frags from wfrag (L2-resident). Epilogue stages f32 acc through
// LDS; each lane owns one (row, head) 32-col segment. NOT fused with the
// bucket scatter — R9 lesson: the scatter needs max-TLP (32 waves/CU of a
// tiny kernel), co-residence with a 33KB-LDS kernel starves it.
// ---------------------------------------------------------------------------
__global__ __launch_bounds__(256) void gemm_alpha_kernel(
    const float* __restrict__ x,       // [N,128] fp32
    const unsigned int* __restrict__ wfrag,
    const float* __restrict__ biasc,
    const float* __restrict__ asrc,
    const float* __restrict__ adst,
    unsigned int* __restrict__ xtb,    // [N,64] uints = [N,128] bf16
    float* __restrict__ alpha_src,     // [N,4]
    float* __restrict__ alpha_dst,     // [N,4]
    int n)
{
    __shared__ __align__(16) float C[64 * 132];   // 33 KB, stride 132 (pad)
    int tid  = threadIdx.x;
    int lane = tid & 63;
    int wave = tid >> 6;
    int quad = lane >> 4;
    int lm   = lane & 15;
    int m0   = blockIdx.x * 64 + wave * 16;

    f32x4 acc[8];
    #pragma unroll
    for (int t = 0; t < 8; ++t) acc[t] = (f32x4){0.f, 0.f, 0.f, 0.f};

    int arow = m0 + lm; if (arow >= n) arow = n - 1;   // clamp (stores masked)
    const float4* xr = (const float4*)(x + (size_t)arow * 128 + quad * 8);
    const uint4*  wf = (const uint4*)wfrag;

    #pragma unroll
    for (int ks = 0; ks < 4; ++ks) {
        float4 a0 = xr[ks * 8 + 0];    // k = ks*32 + quad*8 + 0..3
        float4 a1 = xr[ks * 8 + 1];    // k = ks*32 + quad*8 + 4..7
        U4 af;
        af.u.x = pack_bf16(a0.x, a0.y);
        af.u.y = pack_bf16(a0.z, a0.w);
        af.u.z = pack_bf16(a1.x, a1.y);
        af.u.w = pack_bf16(a1.z, a1.w);
        #pragma unroll
        for (int nt = 0; nt < 8; ++nt) {
            U4 bf; bf.u = wf[(nt * 4 + ks) * 64 + lane];
            acc[nt] = __builtin_amdgcn_mfma_f32_16x16x32_bf16(
                af.v, bf.v, acc[nt], 0, 0, 0);
        }
    }

    // stage accumulators to LDS: C/D layout col = lane&15, row = quad*4+reg
    #pragma unroll
    for (int nt = 0; nt < 8; ++nt) {
        int col = nt * 16 + lm;
        #pragma unroll
        for (int r = 0; r < 4; ++r) {
            int rowl = wave * 16 + quad * 4 + r;
            C[rowl * 132 + col] = acc[nt][r];
        }
    }
    __syncthreads();

    // epilogue: 4 lanes per row; lane's segment = head (seg = lane&3)
    int rowl = wave * 16 + (lane >> 2);
    int seg  = lane & 3;
    int mrow = blockIdx.x * 64 + rowl;
    if (mrow < n) {
        const float4* cb = (const float4*)(C + rowl * 132 + seg * 32);
        const float4* bb = (const float4*)(biasc + seg * 32);
        const float4* sb = (const float4*)(asrc + seg * 32);
        const float4* db = (const float4*)(adst + seg * 32);
        float s = 0.f, d = 0.f;
        unsigned int ow[16];
        #pragma unroll
        for (int q = 0; q < 8; ++q) {
            float4 v = cb[q];
            float4 b = bb[q];
            v.x += b.x; v.y += b.y; v.z += b.z; v.w += b.w;
            float4 as = sb[q], ad = db[q];
            s += v.x * as.x + v.y * as.y + v.z * as.z + v.w * as.w;
            d += v.x * ad.x + v.y * ad.y + v.z * ad.z + v.w * ad.w;
            ow[q * 2 + 0] = pack_bf16(v.x, v.y);
            ow[q * 2 + 1] = pack_bf16(v.z, v.w);
        }
        alpha_src[mrow * 4 + seg] = s;
        alpha_dst[mrow * 4 + seg] = d;
        uint4* xo = (uint4*)(xtb + (size_t)mrow * 64 + seg * 16);
        #pragma unroll
        for (int q4 = 0; q4 < 4; ++q4)
            xo[q4] = make_uint4(ow[q4 * 4], ow[q4 * 4 + 1],
                                ow[q4 * 4 + 2], ow[q4 * 4 + 3]);
    }
}

// ---------------------------------------------------------------------------
// Kernel 3: bucket scatter — fixed 96-slot buckets per destination.
// 1 edge/thread, 8 VGPR -> ~32 waves/CU TLP to hide atomic+store latency.
// ---------------------------------------------------------------------------
__global__ __launch_bounds__(256) void bucket_kernel(
    const int* __restrict__ ei, int* __restrict__ cnt,
    int* __restrict__ esrc, int ne)
{
    int e = blockIdx.x * 256 + threadIdx.x;
    if (e >= ne) return;
    int row = ei[e], col = ei[ne + e];
    int pos = atomicAdd(&cnt[col], 1);
    if (pos < BUCKET) esrc[col * BUCKET + pos] = row;   // u32 index (< 4.8M)
}

// ---------------------------------------------------------------------------
// Kernel 4: fused softmax + aggregation. TWO nodes per wave (32 lanes /
// node, 4 ch/lane via uint2) -> up to 16 independent edge-gather chains in
// flight per wave (2 nodes x unroll 8), 2x R8's per-wave MLP. Same line
// traffic per edge (256B = 4 lines). All index math 32-bit.
// ---------------------------------------------------------------------------
__device__ __forceinline__ void edge_math2(
    unsigned int r, unsigned int h, unsigned int sl, float ad,
    const unsigned int* __restrict__ xtb,
    const float* __restrict__ alpha_src,
    float& den, float4& acc)
{
    float as = alpha_src[(r << 2) | h];
    uint2 u = *(const uint2*)(xtb + (r << 6) + (sl << 1));
    float a = as + ad;
    a = fmaxf(a, NEG_SLOPE * a);              // leaky-relu, branchless
    float ex = __expf(a);
    den += ex;
    acc.x = fmaf(ex, __uint_as_float(u.x << 16), acc.x);
    acc.y = fmaf(ex, __uint_as_float(u.x & 0xFFFF0000u), acc.y);
    acc.z = fmaf(ex, __uint_as_float(u.y << 16), acc.z);
    acc.w = fmaf(ex, __uint_as_float(u.y & 0xFFFF0000u), acc.w);
}

__global__ __launch_bounds__(256) void agg_kernel(
    const int* __restrict__ cnt,
    const int* __restrict__ esrc,
    const unsigned int* __restrict__ xtb,   // [N,64] uints (bf16 pairs)
    const float* __restrict__ alpha_src,
    const float* __restrict__ alpha_dst,
    float* __restrict__ out,          // [N,128]
    int n)
{
    int wave = threadIdx.x >> 6;
    unsigned int lane = threadIdx.x & 63;
    unsigned int sub = lane >> 5;          // which node within the wave
    unsigned int sl  = lane & 31;          // channel group 4*sl .. 4*sl+3
    int node = blockIdx.x * 8 + wave * 2 + (int)sub;
    bool active = node < n;
    int nodec = active ? node : 0;
    unsigned int h = sl >> 3;              // 8 lanes per head

    float ad = alpha_dst[((unsigned)nodec << 2) | h];
    const int* eb = esrc + nodec * BUCKET;
    int m = active ? cnt[nodec] : 0; if (m > BUCKET) m = BUCKET;

    float4 acc = make_float4(0.f, 0.f, 0.f, 0.f);
    float den = 0.f;
    int j = 0;
    for (; j + 8 <= m; j += 8) {
        int4 ra = *(const int4*)(eb + j);
        int4 rb = *(const int4*)(eb + j + 4);
        // issue all 16 loads up front (8 alpha + 8 xtb uint2 chains)
        float as0 = alpha_src[((unsigned)ra.x << 2) | h];
        float as1 = alpha_src[((unsigned)ra.y << 2) | h];
        float as2 = alpha_src[((unsigned)ra.z << 2) | h];
        float as3 = alpha_src[((unsigned)ra.w << 2) | h];
        float as4 = alpha_src[((unsigned)rb.x << 2) | h];
        float as5 = alpha_src[((unsigned)rb.y << 2) | h];
        float as6 = alpha_src[((unsigned)rb.z << 2) | h];
        float as7 = alpha_src[((unsigned)rb.w << 2) | h];
        uint2 u0 = *(const uint2*)(xtb + (((unsigned)ra.x << 6) + (sl << 1)));
        uint2 u1 = *(const uint2*)(xtb + (((unsigned)ra.y << 6) + (sl << 1)));
        uint2 u2 = *(const uint2*)(xtb + (((unsigned)ra.z << 6) + (sl << 1)));
        uint2 u3 = *(const uint2*)(xtb + (((unsigned)ra.w << 6) + (sl << 1)));
        uint2 u4 = *(const uint2*)(xtb + (((unsigned)rb.x << 6) + (sl << 1)));
        uint2 u5 = *(const uint2*)(xtb + (((unsigned)rb.y << 6) + (sl << 1)));
        uint2 u6 = *(const uint2*)(xtb + (((unsigned)rb.z << 6) + (sl << 1)));
        uint2 u7 = *(const uint2*)(xtb + (((unsigned)rb.w << 6) + (sl << 1)));
        float a0 = fmaxf(as0 + ad, NEG_SLOPE * (as0 + ad));
        float a1 = fmaxf(as1 + ad, NEG_SLOPE * (as1 + ad));
        float a2 = fmaxf(as2 + ad, NEG_SLOPE * (as2 + ad));
        float a3 = fmaxf(as3 + ad, NEG_SLOPE * (as3 + ad));
        float a4 = fmaxf(as4 + ad, NEG_SLOPE * (as4 + ad));
        float a5 = fmaxf(as5 + ad, NEG_SLOPE * (as5 + ad));
        float a6 = fmaxf(as6 + ad, NEG_SLOPE * (as6 + ad));
        float a7 = fmaxf(as7 + ad, NEG_SLOPE * (as7 + ad));
        float e0 = __expf(a0), e1 = __expf(a1), e2 = __expf(a2), e3 = __expf(a3);
        float e4 = __expf(a4), e5 = __expf(a5), e6 = __expf(a6), e7 = __expf(a7);
        den += ((e0 + e1) + (e2 + e3)) + ((e4 + e5) + (e6 + e7));
        acc.x = fmaf(e0, __uint_as_float(u0.x << 16),
                fmaf(e1, __uint_as_float(u1.x << 16),
                fmaf(e2, __uint_as_float(u2.x << 16),
                fmaf(e3, __uint_as_float(u3.x << 16),
                fmaf(e4, __uint_as_float(u4.x << 16),
                fmaf(e5, __uint_as_float(u5.x << 16),
                fmaf(e6, __uint_as_float(u6.x << 16),
                fmaf(e7, __uint_as_float(u7.x << 16), acc.x))))))));
        acc.y = fmaf(e0, __uint_as_float(u0.x & 0xFFFF0000u),
                fmaf(e1, __uint_as_float(u1.x & 0xFFFF0000u),
                fmaf(e2, __uint_as_float(u2.x & 0xFFFF0000u),
                fmaf(e3, __uint_as_float(u3.x & 0xFFFF0000u),
                fmaf(e4, __uint_as_float(u4.x & 0xFFFF0000u),
                fmaf(e5, __uint_as_float(u5.x & 0xFFFF0000u),
                fmaf(e6, __uint_as_float(u6.x & 0xFFFF0000u),
                fmaf(e7, __uint_as_float(u7.x & 0xFFFF0000u), acc.y))))))));
        acc.z = fmaf(e0, __uint_as_float(u0.y << 16),
                fmaf(e1, __uint_as_float(u1.y << 16),
                fmaf(e2, __uint_as_float(u2.y << 16),
                fmaf(e3, __uint_as_float(u3.y << 16),
                fmaf(e4, __uint_as_float(u4.y << 16),
                fmaf(e5, __uint_as_float(u5.y << 16),
                fmaf(e6, __uint_as_float(u6.y << 16),
                fmaf(e7, __uint_as_float(u7.y << 16), acc.z))))))));
        acc.w = fmaf(e0, __uint_as_float(u0.y & 0xFFFF0000u),
                fmaf(e1, __uint_as_float(u1.y & 0xFFFF0000u),
                fmaf(e2, __uint_as_float(u2.y & 0xFFFF0000u),
                fmaf(e3, __uint_as_float(u3.y & 0xFFFF0000u),
                fmaf(e4, __uint_as_float(u4.y & 0xFFFF0000u),
                fmaf(e5, __uint_as_float(u5.y & 0xFFFF0000u),
                fmaf(e6, __uint_as_float(u6.y & 0xFFFF0000u),
                fmaf(e7, __uint_as_float(u7.y & 0xFFFF0000u), acc.w))))))));
    }
    if (j + 4 <= m) {
        int4 ra = *(const int4*)(eb + j);
        edge_math2(ra.x, h, sl, ad, xtb, alpha_src, den, acc);
        edge_math2(ra.y, h, sl, ad, xtb, alpha_src, den, acc);
        edge_math2(ra.z, h, sl, ad, xtb, alpha_src, den, acc);
        edge_math2(ra.w, h, sl, ad, xtb, alpha_src, den, acc);
        j += 4;
    }
    for (; j < m; ++j)
        edge_math2(eb[j], h, sl, ad, xtb, alpha_src, den, acc);

    if (active) {
        float inv = 1.0f / (den + 1e-16f);
        ((float4*)out)[((unsigned)node << 5) | sl] =
            make_float4(acc.x * inv, acc.y * inv, acc.z * inv, acc.w * inv);
    }
}

// ---------------------------------------------------------------------------
extern "C" void kernel_launch(void* const* d_in, const int* in_sizes, int n_in,
                              void* d_out, int out_size, void* d_ws, size_t ws_size,
                              hipStream_t stream)
{
    const float* x      = (const float*)d_in[0];
    const int*   ei     = (const int*)  d_in[1];
    const float* coeffs = (const float*)d_in[2];
    const float* lw     = (const float*)d_in[3];
    const float* lb     = (const float*)d_in[4];
    const float* asr    = (const float*)d_in[5];
    const float* ads    = (const float*)d_in[6];
    float* out = (float*)d_out;

    int n  = in_sizes[0] / GAT_IN;     // 50000
    int ne = in_sizes[1] / 2;          // 600000

    // workspace layout (16B-aligned segments)
    float* ws        = (float*)d_ws;
    unsigned int* wfrag = (unsigned int*)ws;      // 8192 uints (32 KB)
    float* biasc     = ws + 16384;                // 128
    float* asrc      = ws + 16512;                // 128
    float* adst      = ws + 16640;                // 128
    unsigned int* xtb = (unsigned int*)(ws + 16768);      // n*64 uints
    float* alpha_src = (float*)(xtb + (size_t)n * 64);    // n*4
    float* alpha_dst = alpha_src + (size_t)n * 4;         // n*4
    int*   cnt       = (int*)(alpha_dst + (size_t)n * 4); // n
    int*   esrc      = cnt + n;                   // n*BUCKET

    // 1. interpolate params (W in B-frag bf16 order) + zero cnt
    int zb = (n + 255) / 256; if (zb < 64) zb = 64;
    interp_kernel<<<zb, 256, 0, stream>>>(coeffs, lw, lb, asr, ads,
                                          wfrag, biasc, asrc, adst, cnt, n);
    // 2. MFMA GEMM + alpha (64 rows/block, x read once)
    gemm_alpha_kernel<<<(n + 63) / 64, 256, 0, stream>>>(
        x, wfrag, biasc, asrc, adst, xtb, alpha_src, alpha_dst, n);
    // 3. bucket scatter (standalone, max TLP)
    bucket_kernel<<<(ne + 255) / 256, 256, 0, stream>>>(ei, cnt, esrc, ne);
    // 4. fused softmax + aggregation (2 nodes per wave)
    agg_kernel<<<(n + 7) / 8, 256, 0, stream>>>(
        cnt, esrc, xtb, alpha_src, alpha_dst, out, n);
}